// Round 12
// baseline (35.895 us; speedup 1.0000x reference)
//
#include <hip/hip_runtime.h>

// EnergyPool2d: N=16, C=64, H=W=128, 3x3 windows stride 1 -> Ho=Wo=126.
// +1 at first-argmax flat index, -1 at first-argmin flat index per window.
// R12: fine-grain inter-block phase mixing. 256-thread blocks own a
// quarter-plane strip (32 rows, 16KB LDS count): 4096 blocks, 8 resident
// per CU (wave cap) -> resident blocks naturally sit in different
// zero/compute/write phases, overlapping VALU with HBM chip-wide.
// Seam: quarters recompute up to 2 boundary window-rows; the LDS
// ownership guard (0 <= flat-bias < 4096) resolves attribution (R8).

#define HH 128
#define WW 128
#define PLANE (HH * WW)     // 16384
#define QROWS 32
#define QPLANE (QROWS * WW) // 4096 ints = 16 KB
#define NPLANES (16 * 64)   // 1024
#define BLOCK 256

// First-occurrence argmax/argmin over a 3x3 window, row-major scan order
// (strict > / <). Adds guarded by quarter-strip ownership.
__device__ __forceinline__ void scan9(float w0, float w1, float w2,
                                      float w3, float w4, float w5,
                                      float w6, float w7, float w8,
                                      int base, int bias, int* __restrict__ cnt) {
    float vmax = w0, vmin = w0;
    int omax = 0, omin = 0;
#define STEP(v, off)                                      \
    do {                                                  \
        if ((v) > vmax) { vmax = (v); omax = (off); }     \
        if ((v) < vmin) { vmin = (v); omin = (off); }     \
    } while (0)
    STEP(w1, 1);
    STEP(w2, 2);
    STEP(w3, WW);
    STEP(w4, WW + 1);
    STEP(w5, WW + 2);
    STEP(w6, 2 * WW);
    STEP(w7, 2 * WW + 1);
    STEP(w8, 2 * WW + 2);
#undef STEP
    const int iM = base + omax - bias;
    if ((unsigned)iM < QPLANE) atomicAdd(&cnt[iM], 1);
    const int im = base + omin - bias;
    if ((unsigned)im < QPLANE) atomicAdd(&cnt[im], -1);
}

__global__ __launch_bounds__(BLOCK, 8)
void energy_pool2d_kernel(const float* __restrict__ x, float* __restrict__ out) {
    __shared__ int cnt[QPLANE]; // 16 KB

    const int tid = threadIdx.x;
    const int plane = blockIdx.x >> 2;
    const int q = blockIdx.x & 3;
    const float* __restrict__ xp = x + (size_t)plane * PLANE;

    // Zero the LDS quarter-strip.
    int4* c4 = (int4*)cnt;
#pragma unroll
    for (int i = 0; i < QPLANE / 4 / BLOCK; ++i)
        c4[tid + i * BLOCK] = make_int4(0, 0, 0, 0);
    __syncthreads();

    // Owned plane rows [q*32, q*32+32). Windows whose 3x3 footprint touches
    // the owned rows have top row in [q*32-2, q*32+31] (clipped to [0,125]).
    const int bias = q * QPLANE;
    const int wr_begin = (q == 0) ? 0 : (q * QROWS - 2);
    const int wr_endx = (q == 3) ? 126 : (q * QROWS + QROWS); // exclusive
    const int rtcnt = (wr_endx - wr_begin) >> 1;  // 16 or 17
    const int ntiles = rtcnt * 32;                // 512 or 544

    for (int t = tid; t < ntiles; t += BLOCK) {
        const int rt = t >> 5;
        const int ct = t & 31;
        const int wr0 = wr_begin + rt * 2;  // window rows wr0, wr0+1 (<=125)
        const int j0 = ct * 4;
        const float* __restrict__ p = xp + wr0 * WW + j0;

        // 4 input rows x 8 cols; right float4 skipped at the right edge
        // (ct=31 -> windows at cols 124,125 only; keeps loads in-bounds).
        const float4 a0 = *(const float4*)(p);
        const float4 a1 = *(const float4*)(p + WW);
        const float4 a2 = *(const float4*)(p + 2 * WW);
        const float4 a3 = *(const float4*)(p + 3 * WW);
        float4 b0, b1, b2, b3;
        if (ct < 31) {
            b0 = *(const float4*)(p + 4);
            b1 = *(const float4*)(p + WW + 4);
            b2 = *(const float4*)(p + 2 * WW + 4);
            b3 = *(const float4*)(p + 3 * WW + 4);
        } else {
            b0 = b1 = b2 = b3 = make_float4(0.f, 0.f, 0.f, 0.f);
        }
        const float r0[8] = {a0.x, a0.y, a0.z, a0.w, b0.x, b0.y, b0.z, b0.w};
        const float r1[8] = {a1.x, a1.y, a1.z, a1.w, b1.x, b1.y, b1.z, b1.w};
        const float r2[8] = {a2.x, a2.y, a2.z, a2.w, b2.x, b2.y, b2.z, b2.w};
        const float r3[8] = {a3.x, a3.y, a3.z, a3.w, b3.x, b3.y, b3.z, b3.w};

        const int nw = (ct < 31) ? 4 : 2;
        const int base0 = wr0 * WW + j0;
#pragma unroll
        for (int c = 0; c < 4; ++c) {
            if (c < nw) {
                scan9(r0[c], r0[c + 1], r0[c + 2],
                      r1[c], r1[c + 1], r1[c + 2],
                      r2[c], r2[c + 1], r2[c + 2], base0 + c, bias, cnt);
                scan9(r1[c], r1[c + 1], r1[c + 2],
                      r2[c], r2[c + 1], r2[c + 2],
                      r3[c], r3[c + 1], r3[c + 2], base0 + WW + c, bias, cnt);
            }
        }
    }
    __syncthreads();

    // Coalesced writeout of this quarter (fully overwritten -> no pre-zero).
    float4* __restrict__ o4 = (float4*)(out + (size_t)plane * PLANE + bias);
#pragma unroll
    for (int i = 0; i < QPLANE / 4 / BLOCK; ++i) {
        const int4 ci = c4[tid + i * BLOCK];
        o4[tid + i * BLOCK] =
            make_float4((float)ci.x, (float)ci.y, (float)ci.z, (float)ci.w);
    }
}

extern "C" void kernel_launch(void* const* d_in, const int* in_sizes, int n_in,
                              void* d_out, int out_size, void* d_ws, size_t ws_size,
                              hipStream_t stream) {
    const float* x = (const float*)d_in[0];
    float* out = (float*)d_out;
    energy_pool2d_kernel<<<NPLANES * 4, BLOCK, 0, stream>>>(x, out);
}